// Round 2
// baseline (13723.134 us; speedup 1.0000x reference)
//
#include <hip/hip_runtime.h>
#include <math.h>

// ---------------- problem constants ----------------
#define Bz     64
#define LENS   128
#define LENP   12
#define Tz     140
#define Dz     768
#define NHz    12
#define HDz    64
#define NLz    6
#define DMLPz  3072
#define NCLSz  10
#define EPBz   278                 // edges per batch = 2*(T-1)
#define NTOKz  (Bz*Tz)             // 8960
#define ZDIMz  (Tz*Dz)             // 107520
#define KBIGz  (LENS*Dz)           // 98304
#define KSMALLz (LENP*Dz)          // 9216

__device__ __forceinline__ float wave_sum(float v){
  #pragma unroll
  for (int m = 32; m; m >>= 1) v += __shfl_xor(v, m);
  return v;
}
__device__ __forceinline__ float wave_max(float v){
  #pragma unroll
  for (int m = 32; m; m >>= 1) v = fmaxf(v, __shfl_xor(v, m));
  return v;
}
__device__ __forceinline__ float gelu_tanh(float u){
  float c = 0.7978845608028654f * (u + 0.044715f * u * u * u);
  return 0.5f * u * (1.0f + tanhf(c));
}
__device__ __forceinline__ float gelu_exact(float u){
  return 0.5f * u * (1.0f + erff(u * 0.7071067811865476f));
}

// ---------------- positional encoding (once) ----------------
__global__ void k_pe(float* pe){
  int idx = blockIdx.x * 256 + threadIdx.x;      // < 128*768
  int s = idx / Dz, o = idx % Dz;
  int ie = o & ~1;
  double ang = (double)s * pow(10000.0, -(double)ie / (double)Dz);
  pe[idx] = (o & 1) ? (float)cos(ang) : (float)sin(ang);
}

// transpose conv_w (768,48,3) -> cwt[(k*48+i)*768 + o]
__global__ void k_cwt(const float* __restrict__ cw, float* __restrict__ cwt){
  int idx = blockIdx.x * 256 + threadIdx.x;      // < 144*768
  int o = idx % Dz, j = idx / Dz;                // j = k*48+i
  int i = j % 48, k = j / 48;
  cwt[j * Dz + o] = cw[o * 144 + i * 3 + k];
}

// conv encoder: one block per (b,s); h0[b,s,:] = conv + PE
__global__ __launch_bounds__(256) void k_conv(const float* __restrict__ x_enc,
                                              const float* __restrict__ cwt,
                                              const float* __restrict__ pe,
                                              float* __restrict__ h0){
  int b = blockIdx.x / LENS, s = blockIdx.x % LENS;
  int tid = threadIdx.x;
  __shared__ float in144[144];
  if (tid < 144){
    int k = tid / 48, i = tid % 48;
    int sp = (s + k - 1 + LENS) % LENS;          // circular-padded inp column
    int p = i / 3, m = i % 3;
    int j = sp * 8 + p; if (j > 1023) j = 1023;  // repeat last timestep
    in144[tid] = x_enc[(b * 1024 + j) * 3 + m];
  }
  __syncthreads();
  for (int o = tid; o < Dz; o += 256){
    float acc = pe[s * Dz + o];
    #pragma unroll 8
    for (int j = 0; j < 144; ++j) acc += in144[j] * cwt[j * Dz + o];
    h0[((size_t)(b * Tz + s)) * Dz + o] = acc;
  }
}

__global__ void k_prompt(const float* __restrict__ pr, float* __restrict__ h0){
  int idx = blockIdx.x * 256 + threadIdx.x;      // < 64*12*768
  int b = idx / (LENP * Dz), r = idx % (LENP * Dz);
  h0[((size_t)(b * Tz + LENS)) * Dz + r] = pr[r];
}

// node L2 norms (one wave per node)
__global__ void k_norms(const float* __restrict__ h0, float* __restrict__ nrm){
  int n = blockIdx.x, lane = threadIdx.x;
  const float* r = h0 + (size_t)n * Dz;
  float s = 0.f;
  for (int d = lane; d < Dz; d += 64){ float v = r[d]; s += v * v; }
  s = wave_sum(s);
  if (lane == 0) nrm[n] = sqrtf(s);
}

// per-edge cosine (one wave per edge)
__global__ void k_ecos(const float* __restrict__ h0, const int* __restrict__ eidx,
                       const float* __restrict__ nrm, float* __restrict__ cosb){
  int e = blockIdx.x, lane = threadIdx.x;
  int sN = eidx[e], dN = eidx[Bz * EPBz + e];
  const float* a = h0 + (size_t)sN * Dz;
  const float* b = h0 + (size_t)dN * Dz;
  float s = 0.f;
  for (int d = lane; d < Dz; d += 64) s += a[d] * b[d];
  s = wave_sum(s);
  if (lane == 0) cosb[e] = s / (nrm[sN] * nrm[dN] + 1e-8f);
}

// segment softmax (2 segments per batch), one block per batch
__global__ __launch_bounds__(256) void k_esoft(const float* __restrict__ cosb,
                                               const int* __restrict__ eseg,
                                               float* __restrict__ ew){
  int b = blockIdx.x, tid = threadIdx.x;
  __shared__ float c[EPBz];
  __shared__ unsigned char gg[EPBz];
  __shared__ float r0[256], r1[256];
  for (int e = tid; e < EPBz; e += 256){
    c[e] = cosb[b * EPBz + e];
    gg[e] = (unsigned char)(eseg[b * EPBz + e] - 2 * b);
  }
  __syncthreads();
  float m0 = -1e30f, m1 = -1e30f;
  for (int e = tid; e < EPBz; e += 256){
    if (gg[e]) m1 = fmaxf(m1, c[e]); else m0 = fmaxf(m0, c[e]);
  }
  r0[tid] = m0; r1[tid] = m1; __syncthreads();
  for (int s = 128; s; s >>= 1){
    if (tid < s){ r0[tid] = fmaxf(r0[tid], r0[tid+s]); r1[tid] = fmaxf(r1[tid], r1[tid+s]); }
    __syncthreads();
  }
  m0 = r0[0]; m1 = r1[0]; __syncthreads();
  float s0 = 0.f, s1 = 0.f;
  for (int e = tid; e < EPBz; e += 256){
    float ex = expf(c[e] - (gg[e] ? m1 : m0));
    c[e] = ex;
    if (gg[e]) s1 += ex; else s0 += ex;
  }
  r0[tid] = s0; r1[tid] = s1; __syncthreads();
  for (int s = 128; s; s >>= 1){
    if (tid < s){ r0[tid] += r0[tid+s]; r1[tid] += r1[tid+s]; }
    __syncthreads();
  }
  s0 = r0[0]; s1 = r1[0];
  for (int e = tid; e < EPBz; e += 256)
    ew[b * EPBz + e] = c[e] / ((gg[e] ? s1 : s0) + 1e-8f);
}

// s init with both biases
__global__ void k_fills(const float* __restrict__ b1, const float* __restrict__ b0,
                        float* __restrict__ sbuf){
  int idx = blockIdx.x * 256 + threadIdx.x;      // < 64*768
  int d = idx % Dz;
  sbuf[idx] = b1[d] + b0[d];
}

// split-K GEMM: C(64x768) += A(64 x K) @ W(K x 768); A rows stride ZDIM in h0
__global__ __launch_bounds__(256) void k_splitk(const float* __restrict__ Abase, int aOff,
                                                const float* __restrict__ W,
                                                float* __restrict__ Cacc,
                                                int K, int kChunk){
  __shared__ __align__(16) float As[16 * 65];
  __shared__ __align__(16) float Ws[16 * 64];
  int tid = threadIdx.x, tx = tid % 16, ty = tid / 16;
  int n0 = blockIdx.x * 64;
  int kb = blockIdx.y * kChunk;
  int ke = kb + kChunk; if (ke > K) ke = K;
  float acc[16];
  #pragma unroll
  for (int i = 0; i < 16; ++i) acc[i] = 0.f;
  for (int kk = kb; kk < ke; kk += 16){
    // FIXED (round 1 bug): stage the FULL 16k x 64m A-tile — 4 elems/thread.
    #pragma unroll
    for (int r = 0; r < 4; ++r){
      int idx = tid + r * 256; int k = idx & 15, m = idx >> 4;   // m in [0,64)
      As[k * 65 + m] = Abase[(size_t)m * ZDIMz + aOff + kk + k];
    }
    #pragma unroll
    for (int r = 0; r < 4; ++r){
      int idx = tid + r * 256; int n = idx & 63, k = idx >> 6;
      Ws[k * 64 + n] = W[(size_t)(kk + k) * Dz + n0 + n];
    }
    __syncthreads();
    #pragma unroll
    for (int k = 0; k < 16; ++k){
      float a[4], bvv[4];
      #pragma unroll
      for (int i = 0; i < 4; ++i) a[i] = As[k * 65 + ty * 4 + i];
      #pragma unroll
      for (int j = 0; j < 4; ++j) bvv[j] = Ws[k * 64 + tx * 4 + j];
      #pragma unroll
      for (int i = 0; i < 4; ++i)
        #pragma unroll
        for (int j = 0; j < 4; ++j) acc[i * 4 + j] += a[i] * bvv[j];
    }
    __syncthreads();
  }
  #pragma unroll
  for (int i = 0; i < 4; ++i)
    #pragma unroll
    for (int j = 0; j < 4; ++j)
      atomicAdd(&Cacc[(size_t)(ty * 4 + i) * Dz + n0 + tx * 4 + j], acc[i * 4 + j]);
}

// P[b,d] = sum_{c<128} s[b,c]*l2s_w[c,d]
__global__ void k_psmall(const float* __restrict__ sbuf, const float* __restrict__ l2sw,
                         float* __restrict__ P){
  int idx = blockIdx.x * 256 + threadIdx.x;      // < 64*768
  int b = idx / Dz, d = idx % Dz;
  float acc = 0.f;
  #pragma unroll 8
  for (int c = 0; c < 128; ++c) acc += sbuf[b * Dz + c] * l2sw[c * Dz + d];
  P[idx] = acc;
}

__global__ void k_addwpe(const float* __restrict__ h0, const float* __restrict__ wpe,
                         float* __restrict__ h){
  size_t idx = (size_t)blockIdx.x * 256 + threadIdx.x;   // < NTOK*D
  int n = (int)(idx / Dz), d = (int)(idx % Dz);
  int t = n % Tz;
  h[idx] = h0[idx] + wpe[t * Dz + d];
}

// row layernorm over D=768, block per row (3 elems per thread)
__global__ __launch_bounds__(256) void k_ln(const float* __restrict__ in, float* __restrict__ out,
                                            const float* __restrict__ g, const float* __restrict__ bb){
  int row = blockIdx.x, tid = threadIdx.x;
  const float* r = in + (size_t)row * Dz;
  float v0 = r[tid], v1 = r[tid + 256], v2 = r[tid + 512];
  __shared__ float red[256];
  red[tid] = v0 + v1 + v2; __syncthreads();
  for (int s = 128; s; s >>= 1){ if (tid < s) red[tid] += red[tid + s]; __syncthreads(); }
  float mu = red[0] * (1.0f / Dz); __syncthreads();
  float d0 = v0 - mu, d1 = v1 - mu, d2 = v2 - mu;
  red[tid] = d0 * d0 + d1 * d1 + d2 * d2; __syncthreads();
  for (int s = 128; s; s >>= 1){ if (tid < s) red[tid] += red[tid + s]; __syncthreads(); }
  float rstd = rsqrtf(red[0] * (1.0f / Dz) + 1e-5f);
  float* o = out + (size_t)row * Dz;
  o[tid]       = d0 * rstd * g[tid]       + bb[tid];
  o[tid + 256] = d1 * rstd * g[tid + 256] + bb[tid + 256];
  o[tid + 512] = d2 * rstd * g[tid + 512] + bb[tid + 512];
}

// generic fp32 GEMM, 128x128 tile, BK=16, 8x8 per thread.
// MODE 0: C = A@W + bias
// MODE 1: C = R + A@W + bias
// MODE 2: C = gelu_tanh(A@W + bias)
// MODE 3: C = R + A@W + bias + w_l2s*c_t*(lscale*P[b,col] + l2sb[col])
template<int MODE>
__global__ __launch_bounds__(256) void k_gemm(const float* __restrict__ A, const float* __restrict__ W,
                                              const float* __restrict__ bias, const float* __restrict__ R,
                                              float* __restrict__ C, int M, int N, int K,
                                              const float* __restrict__ P, const float* __restrict__ l2sb,
                                              const float* __restrict__ wl2s, float lscale){
  __shared__ __align__(16) float As[16 * 132];
  __shared__ __align__(16) float Ws[16 * 128];
  int tid = threadIdx.x, tx = tid % 16, ty = tid / 16;
  int n0 = blockIdx.x * 128, m0 = blockIdx.y * 128;
  float acc[64];
  #pragma unroll
  for (int i = 0; i < 64; ++i) acc[i] = 0.f;
  for (int kk = 0; kk < K; kk += 16){
    #pragma unroll
    for (int p = 0; p < 8; ++p){
      int idx = tid + p * 256; int k = idx & 15, m = idx >> 4;
      As[k * 132 + m] = A[(size_t)(m0 + m) * K + kk + k];
    }
    #pragma unroll
    for (int p = 0; p < 8; ++p){
      int idx = tid + p * 256; int n = idx & 127, k = idx >> 7;
      Ws[k * 128 + n] = W[(size_t)(kk + k) * N + n0 + n];
    }
    __syncthreads();
    #pragma unroll
    for (int k = 0; k < 16; ++k){
      float4 a0 = *(const float4*)&As[k * 132 + ty * 8];
      float4 a1 = *(const float4*)&As[k * 132 + ty * 8 + 4];
      float4 b0 = *(const float4*)&Ws[k * 128 + tx * 8];
      float4 b1 = *(const float4*)&Ws[k * 128 + tx * 8 + 4];
      float av[8] = {a0.x,a0.y,a0.z,a0.w,a1.x,a1.y,a1.z,a1.w};
      float bv[8] = {b0.x,b0.y,b0.z,b0.w,b1.x,b1.y,b1.z,b1.w};
      #pragma unroll
      for (int i = 0; i < 8; ++i)
        #pragma unroll
        for (int j = 0; j < 8; ++j) acc[i * 8 + j] += av[i] * bv[j];
    }
    __syncthreads();
  }
  float wv = 0.f;
  if (MODE == 3) wv = wl2s[0];
  #pragma unroll
  for (int i = 0; i < 8; ++i){
    int row = m0 + ty * 8 + i;
    int col0 = n0 + tx * 8;
    size_t base = (size_t)row * N + col0;
    int b = row / Tz, t = row % Tz;
    float ct = (t < LENS) ? (1.0f / LENS) : (1.0f / LENP);
    #pragma unroll
    for (int j = 0; j < 8; ++j){
      float v = acc[i * 8 + j] + bias[col0 + j];
      if (MODE == 1) v += R[base + j];
      if (MODE == 2) v = gelu_tanh(v);
      if (MODE == 3){
        v += R[base + j];
        v += wv * ct * (lscale * P[b * Dz + col0 + j] + l2sb[col0 + j]);
      }
      C[base + j] = v;
    }
  }
}

// fused causal attention for one (b,h): scores+softmax (K in LDS, probs->global),
// then O = P@V (V in LDS).
__global__ __launch_bounds__(256) void k_attn(const float* __restrict__ qkv,
                                              float* __restrict__ probs,
                                              float* __restrict__ obuf){
  int bh = blockIdx.x; int b = bh / NHz, hh = bh % NHz;
  int tid = threadIdx.x, w = tid >> 6, lane = tid & 63;
  __shared__ float KV[HDz * (Tz + 1)];           // phase1: Kt[d][j] (stride 141); phase2: V[j][d]
  const float* base = qkv + (size_t)b * Tz * (3 * Dz);
  // stage K transposed
  for (int idx = tid; idx < Tz * HDz; idx += 256){
    int j = idx >> 6, d = idx & 63;
    KV[d * (Tz + 1) + j] = base[(size_t)j * (3 * Dz) + Dz + hh * HDz + d];
  }
  __syncthreads();
  float* pb = probs + (size_t)bh * (Tz * Tz);
  for (int t = w; t < Tz; t += 4){
    const float* qr = base + (size_t)t * (3 * Dz) + hh * HDz;
    int j1 = lane + 64;
    int j2c = (lane + 128 < Tz) ? (lane + 128) : (Tz - 1);
    float a0 = 0.f, a1 = 0.f, a2 = 0.f;
    #pragma unroll 8
    for (int d = 0; d < HDz; ++d){
      float q = qr[d];
      const float* kr = &KV[d * (Tz + 1)];
      a0 += q * kr[lane];
      a1 += q * kr[j1];
      a2 += q * kr[j2c];
    }
    float s0 = (lane       <= t) ? a0 * 0.125f : -1e30f;
    float s1 = (lane + 64  <= t) ? a1 * 0.125f : -1e30f;
    float s2 = (lane + 128 <= t) ? a2 * 0.125f : -1e30f;
    float mx = wave_max(fmaxf(s0, fmaxf(s1, s2)));
    float e0 = (lane       <= t) ? expf(s0 - mx) : 0.f;
    float e1 = (lane + 64  <= t) ? expf(s1 - mx) : 0.f;
    float e2 = (lane + 128 <= t) ? expf(s2 - mx) : 0.f;
    float inv = 1.0f / wave_sum(e0 + e1 + e2);
    pb[t * Tz + lane] = e0 * inv;
    pb[t * Tz + lane + 64] = e1 * inv;
    if (lane + 128 < Tz) pb[t * Tz + lane + 128] = e2 * inv;
  }
  __threadfence_block();
  __syncthreads();
  // stage V
  for (int idx = tid; idx < Tz * HDz; idx += 256){
    int j = idx >> 6, d = idx & 63;
    KV[j * HDz + d] = base[(size_t)j * (3 * Dz) + 2 * Dz + hh * HDz + d];
  }
  __syncthreads();
  for (int t = w; t < Tz; t += 4){
    const float* pr = pb + t * Tz;
    float o = 0.f;
    #pragma unroll 4
    for (int j = 0; j < Tz; ++j) o += pr[j] * KV[j * HDz + lane];
    obuf[(size_t)(b * Tz + t) * Dz + hh * HDz + lane] = o;
  }
}

// chain-graph aggregation: h = h2 + ew_l*h2[t-1] + ew_r*h2[t+1]
__global__ void k_gnn(const float* __restrict__ h2, const float* __restrict__ ew,
                      float* __restrict__ h){
  size_t idx = (size_t)blockIdx.x * 256 + threadIdx.x;   // < NTOK*D
  int n = (int)(idx / Dz);
  int b = n / Tz, t = n % Tz;
  float v = h2[idx];
  if (t >= 1)      v += ew[b * EPBz + 2 * (t - 1)]     * h2[idx - Dz];
  if (t <= Tz - 2) v += ew[b * EPBz + 2 * t + 1]       * h2[idx + Dz];
  h[idx] = v;
}

// final LN + exact gelu
__global__ __launch_bounds__(256) void k_lnfgelu(const float* __restrict__ in, float* __restrict__ out,
                                                 const float* __restrict__ g, const float* __restrict__ bb){
  int row = blockIdx.x, tid = threadIdx.x;
  const float* r = in + (size_t)row * Dz;
  float v0 = r[tid], v1 = r[tid + 256], v2 = r[tid + 512];
  __shared__ float red[256];
  red[tid] = v0 + v1 + v2; __syncthreads();
  for (int s = 128; s; s >>= 1){ if (tid < s) red[tid] += red[tid + s]; __syncthreads(); }
  float mu = red[0] * (1.0f / Dz); __syncthreads();
  float d0 = v0 - mu, d1 = v1 - mu, d2 = v2 - mu;
  red[tid] = d0 * d0 + d1 * d1 + d2 * d2; __syncthreads();
  for (int s = 128; s; s >>= 1){ if (tid < s) red[tid] += red[tid + s]; __syncthreads(); }
  float rstd = rsqrtf(red[0] * (1.0f / Dz) + 1e-5f);
  float* o = out + (size_t)row * Dz;
  o[tid]       = gelu_exact(d0 * rstd * g[tid]       + bb[tid]);
  o[tid + 256] = gelu_exact(d1 * rstd * g[tid + 256] + bb[tid + 256]);
  o[tid + 512] = gelu_exact(d2 * rstd * g[tid + 512] + bb[tid + 512]);
}

// per-batch stats over ZDIM (fp64 accumulation)
__global__ __launch_bounds__(256) void k_zstats(const float* __restrict__ z, float* __restrict__ stat){
  int b = blockIdx.x, tid = threadIdx.x;
  const float* zr = z + (size_t)b * ZDIMz;
  double s = 0.0, q = 0.0;
  for (int k = tid; k < ZDIMz; k += 256){ double v = zr[k]; s += v; q += v * v; }
  __shared__ double rs_[256], rq_[256];
  rs_[tid] = s; rq_[tid] = q; __syncthreads();
  for (int st = 128; st; st >>= 1){
    if (tid < st){ rs_[tid] += rs_[tid + st]; rq_[tid] += rq_[tid + st]; }
    __syncthreads();
  }
  if (tid == 0){
    double mu = rs_[0] / ZDIMz;
    double var = rq_[0] / ZDIMz - mu * mu;
    stat[b] = (float)mu;
    stat[64 + b] = (float)(1.0 / sqrt(var + 1e-5));
  }
}

// head: out[b,:] = LN(z_b)*g+b  @ out_w + out_b
__global__ __launch_bounds__(256) void k_head(const float* __restrict__ z, const float* __restrict__ stat,
                                              const float* __restrict__ lg, const float* __restrict__ lb,
                                              const float* __restrict__ W, const float* __restrict__ ob,
                                              float* __restrict__ out){
  int b = blockIdx.x, tid = threadIdx.x;
  float mu = stat[b], rs = stat[64 + b];
  const float* zr = z + (size_t)b * ZDIMz;
  float acc[NCLSz];
  #pragma unroll
  for (int j = 0; j < NCLSz; ++j) acc[j] = 0.f;
  for (int k = tid; k < ZDIMz; k += 256){
    float v = (zr[k] - mu) * rs * lg[k] + lb[k];
    const float* wr = W + (size_t)k * NCLSz;
    #pragma unroll
    for (int j = 0; j < NCLSz; ++j) acc[j] += v * wr[j];
  }
  __shared__ float red[256];
  for (int j = 0; j < NCLSz; ++j){
    red[tid] = acc[j]; __syncthreads();
    for (int s = 128; s; s >>= 1){ if (tid < s) red[tid] += red[tid + s]; __syncthreads(); }
    if (tid == 0) out[b * NCLSz + j] = red[0] + ob[j];
    __syncthreads();
  }
}

extern "C" void kernel_launch(void* const* d_in, const int* in_sizes, int n_in,
                              void* d_out, int out_size, void* d_ws, size_t ws_size,
                              hipStream_t stream){
  const float* x_enc  = (const float*)d_in[0];
  const float* conv_w = (const float*)d_in[2];
  const float* prompt = (const float*)d_in[3];
  const float* wpe    = (const float*)d_in[4];
  const float* ln1_g  = (const float*)d_in[5];
  const float* ln1_b  = (const float*)d_in[6];
  const float* attn_w = (const float*)d_in[7];
  const float* attn_b = (const float*)d_in[8];
  const float* proj_w = (const float*)d_in[9];
  const float* proj_b = (const float*)d_in[10];
  const float* ln2_g  = (const float*)d_in[11];
  const float* ln2_b  = (const float*)d_in[12];
  const float* fc1_w  = (const float*)d_in[13];
  const float* fc1_b  = (const float*)d_in[14];
  const float* fc2_w  = (const float*)d_in[15];
  const float* fc2_b  = (const float*)d_in[16];
  const float* lnf_g  = (const float*)d_in[17];
  const float* lnf_b  = (const float*)d_in[18];
  const float* ll1_w  = (const float*)d_in[19];
  const float* ll1_b  = (const float*)d_in[20];
  const float* ll0_w  = (const float*)d_in[21];
  const float* ll0_b  = (const float*)d_in[22];
  const float* l2s_w  = (const float*)d_in[23];
  const float* l2s_b  = (const float*)d_in[24];
  const float* w_l2s  = (const float*)d_in[25];
  const float* lnp_g  = (const float*)d_in[26];
  const float* lnp_b  = (const float*)d_in[27];
  const float* out_w  = (const float*)d_in[28];
  const float* out_b  = (const float*)d_in[29];
  const int*   eidx   = (const int*)d_in[30];
  const int*   eseg   = (const int*)d_in[31];
  float* out = (float*)d_out;

  float* ws = (float*)d_ws;
  const size_t SZ_H = (size_t)NTOKz * Dz;            // 6,881,280
  float* h0   = ws;
  float* hbuf = ws + SZ_H;
  float* xb   = ws + 2 * SZ_H;
  float* h2   = ws + 3 * SZ_H;
  float* qkv  = ws + 4 * SZ_H;                       // 20,643,840
  float* big  = qkv + (size_t)NTOKz * 3 * Dz;        // 27,525,120 (probs / mlp mid)
  float* pe   = big + (size_t)NTOKz * DMLPz;
  float* cwt  = pe + (size_t)LENS * Dz;
  float* sbuf = cwt + 144 * Dz;
  float* Pbuf = sbuf + Bz * Dz;
  float* nrm  = Pbuf + Bz * Dz;
  float* cosb = nrm + NTOKz;
  float* ewb  = cosb + Bz * EPBz;
  float* stat = ewb + Bz * EPBz;                     // 128 floats

  // ---- phase A: encoder + graph weights + l2s precompute ----
  k_pe    <<<(LENS * Dz) / 256, 256, 0, stream>>>(pe);
  k_cwt   <<<(144 * Dz) / 256, 256, 0, stream>>>(conv_w, cwt);
  k_conv  <<<Bz * LENS, 256, 0, stream>>>(x_enc, cwt, pe, h0);
  k_prompt<<<(Bz * LENP * Dz) / 256, 256, 0, stream>>>(prompt, h0);
  k_norms <<<NTOKz, 64, 0, stream>>>(h0, nrm);
  k_ecos  <<<Bz * EPBz, 64, 0, stream>>>(h0, eidx, nrm, cosb);
  k_esoft <<<Bz, 256, 0, stream>>>(cosb, eseg, ewb);
  k_fills <<<(Bz * Dz) / 256, 256, 0, stream>>>(ll1_b, ll0_b, sbuf);
  k_splitk<<<dim3(Dz / 64, 96), 256, 0, stream>>>(h0, 0,     ll1_w, sbuf, KBIGz,  1024);
  k_splitk<<<dim3(Dz / 64, 9),  256, 0, stream>>>(h0, KBIGz, ll0_w, sbuf, KSMALLz, 1024);
  k_psmall<<<(Bz * Dz) / 256, 256, 0, stream>>>(sbuf, l2s_w, Pbuf);
  k_addwpe<<<(int)(SZ_H / 256), 256, 0, stream>>>(h0, wpe, hbuf);

  // ---- phase B: 6 transformer layers ----
  for (int l = 0; l < NLz; ++l){
    k_ln<<<NTOKz, 256, 0, stream>>>(hbuf, xb, ln1_g + l * Dz, ln1_b + l * Dz);
    k_gemm<0><<<dim3(3 * Dz / 128, NTOKz / 128), 256, 0, stream>>>(
        xb, attn_w + (size_t)l * Dz * 3 * Dz, attn_b + l * 3 * Dz, nullptr, qkv,
        NTOKz, 3 * Dz, Dz, nullptr, nullptr, nullptr, 0.f);
    k_attn<<<Bz * NHz, 256, 0, stream>>>(qkv, big, xb);
    k_gemm<1><<<dim3(Dz / 128, NTOKz / 128), 256, 0, stream>>>(
        xb, proj_w + (size_t)l * Dz * Dz, proj_b + l * Dz, hbuf, h2,
        NTOKz, Dz, Dz, nullptr, nullptr, nullptr, 0.f);
    k_gnn<<<(int)(SZ_H / 256), 256, 0, stream>>>(h2, ewb, hbuf);
    k_ln<<<NTOKz, 256, 0, stream>>>(hbuf, xb, ln2_g + l * Dz, ln2_b + l * Dz);
    k_gemm<2><<<dim3(DMLPz / 128, NTOKz / 128), 256, 0, stream>>>(
        xb, fc1_w + (size_t)l * Dz * DMLPz, fc1_b + l * DMLPz, nullptr, big,
        NTOKz, DMLPz, Dz, nullptr, nullptr, nullptr, 0.f);
    k_gemm<3><<<dim3(Dz / 128, NTOKz / 128), 256, 0, stream>>>(
        big, fc2_w + (size_t)l * DMLPz * Dz, fc2_b + l * Dz, hbuf, hbuf,
        NTOKz, Dz, DMLPz, Pbuf, l2s_b, w_l2s, (float)(1 << l));
  }

  // ---- phase C: final LN + gelu + big LN + head ----
  k_lnfgelu<<<NTOKz, 256, 0, stream>>>(hbuf, xb, lnf_g, lnf_b);
  k_zstats <<<Bz, 256, 0, stream>>>(xb, stat);
  k_head   <<<Bz, 256, 0, stream>>>(xb, stat, lnp_g, lnp_b, out_w, out_b, out);
}